// Round 6
// baseline (1257.885 us; speedup 1.0000x reference)
//
#include <hip/hip_runtime.h>
#include <stdint.h>

#define N_NODES 50000
#define N_EDGES 800000
#define DMODEL  256
#define FEDGE   64
#define TILE_E  64
#define N_ETILES (N_EDGES / TILE_E)   // 12500
#define NBLK_EDGE 768                 // persistent blocks: 3 blocks/CU on 256 CUs
#define TILE_N  64
#define N_NTILES ((N_NODES + TILE_N - 1) / TILE_N)  // 782
#define NB_SCAN ((N_NODES + 255) / 256)             // 196

typedef short short8 __attribute__((ext_vector_type(8)));
typedef float floatx4 __attribute__((ext_vector_type(4)));
typedef unsigned short ushort_t;
typedef unsigned short ushort4v __attribute__((ext_vector_type(4)));

__device__ __forceinline__ ushort_t f2bf(float f) {
  union { float f; unsigned int i; } v; v.f = f;
  unsigned int x = v.i;
  unsigned int r = x + 0x7fffu + ((x >> 16) & 1u);  // RNE
  return (ushort_t)(r >> 16);
}
__device__ __forceinline__ float bf2f(ushort_t u) {
  union { unsigned int i; float f; } v; v.i = ((unsigned int)u) << 16; return v.f;
}
__device__ __forceinline__ short8 ldg16(const ushort_t* p) {
  return *(const short8*)(const void*)p;
}
__device__ __forceinline__ floatx4 ldf4(const float* p) {
  return *(const floatx4*)(const void*)p;
}

// ---------------------------------------------------------------------------
// prep: M = bf16(W_le @ W_e2), c = W_le @ b_e2 (f32); bf16 copies of weights.
// ---------------------------------------------------------------------------
__global__ void prep_kernel(const float* __restrict__ W_le,
                            const float* __restrict__ W_e2,
                            const float* __restrict__ b_e2,
                            const float* __restrict__ W_e1,
                            const float* __restrict__ W_g1,
                            const float* __restrict__ W_g2,
                            ushort_t* __restrict__ Mw, float* __restrict__ cw,
                            ushort_t* __restrict__ We1bf,
                            ushort_t* __restrict__ Wg1bf,
                            ushort_t* __restrict__ Wg2bf) {
  int d = blockIdx.x, k = threadIdx.x;
  float acc = 0.f;
  for (int j = 0; j < DMODEL; ++j)
    acc += W_le[d * DMODEL + j] * W_e2[j * DMODEL + k];
  Mw[d * DMODEL + k] = f2bf(acc);
  Wg1bf[d * DMODEL + k] = f2bf(W_g1[d * DMODEL + k]);
  Wg2bf[d * DMODEL + k] = f2bf(W_g2[d * DMODEL + k]);
  if (k < FEDGE) We1bf[d * FEDGE + k] = f2bf(W_e1[d * FEDGE + k]);
  if (k == 0) {
    float cc = 0.f;
    for (int j = 0; j < DMODEL; ++j) cc += W_le[d * DMODEL + j] * b_e2[j];
    cw[d] = cc;
  }
}

// x -> bf16 copy (makes the edge gather 2B/elem and L3-resident: 25.6 MB)
__global__ void xconv_kernel(const float* __restrict__ x, ushort_t* __restrict__ xbf) {
  int i = blockIdx.x * blockDim.x + threadIdx.x;   // one float4 per thread
  floatx4 v = ldf4(x + (long)i * 4);
  ushort4v pk = {f2bf(v[0]), f2bf(v[1]), f2bf(v[2]), f2bf(v[3])};
  *(ushort4v*)(void*)(xbf + (long)i * 4) = pk;
}

// ---------------------------------------------------------------------------
// counting sort by dst: histogram -> 3-phase shfl scan -> scatter(perm)
// ---------------------------------------------------------------------------
__global__ void hist_kernel(const int* __restrict__ eidx, int* __restrict__ counts) {
  int e = blockIdx.x * blockDim.x + threadIdx.x;
  if (e < N_EDGES) atomicAdd(counts + eidx[N_EDGES + e], 1);
}

__global__ void scan_block_kernel(const int* __restrict__ counts,
                                  int* __restrict__ cur, int* __restrict__ bsum) {
  __shared__ int wsum[4];
  int i = blockIdx.x * 256 + threadIdx.x;
  int lane = threadIdx.x & 63, wave = threadIdx.x >> 6;
  int v = (i < N_NODES) ? counts[i] : 0;
  int s = v;
#pragma unroll
  for (int off = 1; off <= 32; off <<= 1) {
    int t = __shfl_up(s, off);
    if (lane >= off) s += t;
  }
  if (lane == 63) wsum[wave] = s;
  __syncthreads();
  int woff = 0;
  if (wave > 0) woff += wsum[0];
  if (wave > 1) woff += wsum[1];
  if (wave > 2) woff += wsum[2];
  if (i < N_NODES) cur[i] = s - v + woff;            // block-local exclusive
  if (threadIdx.x == 255) bsum[blockIdx.x] = s + woff;
}

__global__ void scan_total_kernel(const int* __restrict__ bsum, int* __restrict__ bofs) {
  __shared__ int wsum[4];
  int tid = threadIdx.x;
  int lane = tid & 63, wave = tid >> 6;
  int v = (tid < NB_SCAN) ? bsum[tid] : 0;
  int s = v;
#pragma unroll
  for (int off = 1; off <= 32; off <<= 1) {
    int t = __shfl_up(s, off);
    if (lane >= off) s += t;
  }
  if (lane == 63) wsum[wave] = s;
  __syncthreads();
  int woff = 0;
  if (wave > 0) woff += wsum[0];
  if (wave > 1) woff += wsum[1];
  if (wave > 2) woff += wsum[2];
  if (tid < NB_SCAN) bofs[tid] = s - v + woff;
}

__global__ void scan_add_kernel(int* __restrict__ cur, const int* __restrict__ bofs) {
  int i = blockIdx.x * 256 + threadIdx.x;
  if (i < N_NODES) cur[i] += bofs[i >> 8];
}

__global__ void scatter_kernel(const int* __restrict__ eidx, int* __restrict__ cur,
                               int* __restrict__ perm) {
  int e = blockIdx.x * blockDim.x + threadIdx.x;
  if (e < N_EDGES) {
    int d = eidx[N_EDGES + e];
    int pos = atomicAdd(cur + d, 1);
    perm[pos] = e;
  }
}

// ---------------------------------------------------------------------------
// staging helpers for the persistent edge kernel (registers only, no LDS)
// ---------------------------------------------------------------------------
__device__ __forceinline__ void load_tile_ptrs(long ebase, int tid,
                                               const int* __restrict__ perm,
                                               int (&pe4)[4], int& pe1) {
  int r0 = tid >> 4;
#pragma unroll
  for (int p = 0; p < 4; ++p) pe4[p] = perm[ebase + p * 16 + r0];
  if (tid < TILE_E) pe1 = perm[ebase + tid];
}

__device__ __forceinline__ void load_tile_data(int tid, const int (&pe4)[4], int pe1,
                                               const float* __restrict__ eattr,
                                               const int* __restrict__ eidx,
                                               ushort4v (&rawreg)[4], float& polreg,
                                               int& srcreg, int& dstreg) {
  int c = (tid & 15) * 4;
#pragma unroll
  for (int p = 0; p < 4; ++p) {
    const float* sp = eattr + (long)pe4[p] * 65 + 1 + c;
    rawreg[p] = (ushort4v){f2bf(sp[0]), f2bf(sp[1]), f2bf(sp[2]), f2bf(sp[3])};
  }
  if (tid < TILE_E) {
    polreg = eattr[(long)pe1 * 65];
    srcreg = eidx[pe1];
    dstreg = eidx[N_EDGES + pe1];
  }
}

// ---------------------------------------------------------------------------
// edge kernel: persistent blocks (3/CU), XCD-chunked CONTIGUOUS tile ranges.
// aggr flush policy (this round's change): since each block owns a contiguous
// dst-sorted edge range, each dst belongs to exactly one block (except chunk
// boundaries). runsum now CARRIES ACROSS TILES (dst_lds[64] = next tile's
// first dst, staged from the pipeline's dstreg), so each dst is flushed
// exactly once per block: plain STORE for interior dsts (sole owner,
// complete sum -> line written once, no RMW fetch, no L2-thrash rewrite);
// atomicAdd only for the block's first and final flush (boundary dsts).
// R4/R5 counters showed 8x WRITE amplification from L2 capacity-eviction of
// dirty atomic lines during the multi-tile accumulation window.
// ---------------------------------------------------------------------------
template <bool USEBF>
__global__ __launch_bounds__(256, 3)
void edge_kernel(const float* __restrict__ x,
                 const ushort_t* __restrict__ xbf,
                 const int* __restrict__ eidx,
                 const float* __restrict__ eattr,
                 const int* __restrict__ perm,
                 const ushort_t* __restrict__ We1bf,
                 const float* __restrict__ b_e1,
                 const float* __restrict__ b_le,
                 const ushort_t* __restrict__ Mw,
                 const float* __restrict__ cw,
                 float* __restrict__ aggr) {
  __shared__ __align__(16) ushort_t raw_lds[TILE_E * 72];
  __shared__ __align__(16) ushort_t t1_lds[TILE_E * 264];  // reused as msg f32
  __shared__ float pp_lds[TILE_E];
  __shared__ int src_lds[TILE_E];
  __shared__ int dst_lds[TILE_E + 1];

  const int tid  = threadIdx.x;
  const int lane = tid & 63;
  const int wave = tid >> 6;
  const int l16  = lane & 15;
  const int quad = lane >> 4;
  const int dbase = wave * 64;
  const int d_own = dbase + lane;

  // XCD-chunked, balanced tile range (bijective: 768 = 8 XCDs x 96)
  const int pb = blockIdx.x;
  const int lb = (pb & 7) * (NBLK_EDGE / 8) + (pb >> 3);
  const int q  = N_ETILES / NBLK_EDGE;                  // 16
  const int r  = N_ETILES % NBLK_EDGE;                  // 212
  const long tbeg = (long)lb * q + (lb < r ? lb : r);
  const long tend = tbeg + q + (lb < r ? 1 : 0);

  // prologue: stage first tile into registers
  int pe4[4], pe1 = 0;
  ushort4v rawreg[4];
  float polreg = 0.f;
  int srcreg = 0, dstreg = 0;
  load_tile_ptrs(tbeg * TILE_E, tid, perm, pe4, pe1);
  load_tile_data(tid, pe4, pe1, eattr, eidx, rawreg, polreg, srcreg, dstreg);

  float runsum = 0.f;        // carries across halves AND tiles
  bool first_flush = true;   // block's first flush -> atomic (shared boundary)

  for (long t = tbeg; t < tend; ++t) {
    const long tn = t + 1;
    const bool have_next = (tn < tend);

    // issue next tile's perm-pointer loads FIRST (covered by commit+A+GEMM1)
    if (have_next) load_tile_ptrs(tn * TILE_E, tid, perm, pe4, pe1);

    // ---- commit staged registers to LDS (current tile t)
    {
      int r0 = tid >> 4, c = (tid & 15) * 4;
#pragma unroll
      for (int p = 0; p < 4; ++p)
        *(ushort4v*)(void*)(raw_lds + (p * 16 + r0) * 72 + c) = rawreg[p];
      if (tid < TILE_E) {
        pp_lds[tid] = fminf(fmaxf(polreg, 0.f), 1.f) + 0.01f;
        src_lds[tid] = srcreg;
        dst_lds[tid] = dstreg;
      }
    }
    __syncthreads();   // A: staging visible

    // GEMM1 (transposed): t1^T[f][e]
    {
      floatx4 acc1[4][4];
#pragma unroll
      for (int m = 0; m < 4; ++m)
#pragma unroll
        for (int j = 0; j < 4; ++j) acc1[m][j] = (floatx4){0.f, 0.f, 0.f, 0.f};
#pragma unroll
      for (int kt = 0; kt < 2; ++kt) {
        short8 aW[4], bE[4];
#pragma unroll
        for (int m = 0; m < 4; ++m)
          aW[m] = ldg16(We1bf + (dbase + m * 16 + l16) * FEDGE + kt * 32 + quad * 8);
#pragma unroll
        for (int j = 0; j < 4; ++j)
          bE[j] = *(const short8*)(const void*)(raw_lds + (j * 16 + l16) * 72 + kt * 32 + quad * 8);
#pragma unroll
        for (int m = 0; m < 4; ++m)
#pragma unroll
          for (int j = 0; j < 4; ++j)
            acc1[m][j] = __builtin_amdgcn_mfma_f32_16x16x32_bf16(aW[m], bE[j], acc1[m][j], 0, 0, 0);
      }
#pragma unroll
      for (int m = 0; m < 4; ++m) {
        int f0 = dbase + m * 16 + quad * 4;
        floatx4 be1q = ldf4(b_e1 + f0);
#pragma unroll
        for (int j = 0; j < 4; ++j) {
          int e = j * 16 + l16;
          ushort4v pk = {f2bf(fmaxf(acc1[m][j][0] + be1q[0], 0.f)),
                         f2bf(fmaxf(acc1[m][j][1] + be1q[1], 0.f)),
                         f2bf(fmaxf(acc1[m][j][2] + be1q[2], 0.f)),
                         f2bf(fmaxf(acc1[m][j][3] + be1q[3], 0.f))};
          *(ushort4v*)(void*)(t1_lds + e * 264 + f0) = pk;
        }
      }
    }
    __syncthreads();   // B: t1 ready (acc1 dead here)

    // PREFETCH x[src] fragments (consumed after C; covered by GEMM2)
    ushort4v xpb[4][4];
    floatx4  xpf[4][4];
#pragma unroll
    for (int j = 0; j < 4; ++j) {
      long srow = (long)src_lds[j * 16 + l16] * DMODEL;
#pragma unroll
      for (int m = 0; m < 4; ++m) {
        int d0 = dbase + m * 16 + quad * 4;
        if constexpr (USEBF)
          xpb[j][m] = *(const ushort4v*)(const void*)(xbf + srow + d0);
        else
          xpf[j][m] = ldf4(x + srow + d0);
      }
    }
    // issue next tile's dependent gathers (covered by GEMM2)
    if (have_next)
      load_tile_data(tid, pe4, pe1, eattr, eidx, rawreg, polreg, srcreg, dstreg);

    // GEMM2 (transposed): pre^T[d][e]
    floatx4 acc2[4][4];
#pragma unroll
    for (int m = 0; m < 4; ++m)
#pragma unroll
      for (int j = 0; j < 4; ++j) acc2[m][j] = (floatx4){0.f, 0.f, 0.f, 0.f};
#pragma unroll
    for (int kt = 0; kt < 8; ++kt) {
      short8 aW[4], bE[4];
#pragma unroll
      for (int m = 0; m < 4; ++m)
        aW[m] = ldg16(Mw + (dbase + m * 16 + l16) * DMODEL + kt * 32 + quad * 8);
#pragma unroll
      for (int j = 0; j < 4; ++j)
        bE[j] = *(const short8*)(const void*)(t1_lds + (j * 16 + l16) * 264 + kt * 32 + quad * 8);
#pragma unroll
      for (int m = 0; m < 4; ++m)
#pragma unroll
        for (int j = 0; j < 4; ++j)
          acc2[m][j] = __builtin_amdgcn_mfma_f32_16x16x32_bf16(aW[m], bE[j], acc2[m][j], 0, 0, 0);
    }
    __syncthreads();   // C: t1 dead; LDS reused as per-wave msg buffer

    // publish next tile's first dst into the carry slot (read after barrier D/F)
    if (tid == 0) dst_lds[TILE_E] = have_next ? dstreg : -9;

    floatx4 cv4[4], blv4[4];
#pragma unroll
    for (int m = 0; m < 4; ++m) {
      int d0 = dbase + m * 16 + quad * 4;
      cv4[m] = ldf4(cw + d0);
      blv4[m] = ldf4(b_le + d0);
    }
    float* msgw = ((float*)(void*)t1_lds) + wave * (64 * 33);

#pragma unroll
    for (int h = 0; h < 2; ++h) {
#pragma unroll
      for (int jj = 0; jj < 2; ++jj) {
        int j = h * 2 + jj;
        int e = j * 16 + l16;
        float pp = pp_lds[e];
#pragma unroll
        for (int m = 0; m < 4; ++m) {
          int d0 = m * 16 + quad * 4;
          float xr[4];
          if constexpr (USEBF) {
#pragma unroll
            for (int r2 = 0; r2 < 4; ++r2) xr[r2] = bf2f(xpb[j][m][r2]);
          } else {
#pragma unroll
            for (int r2 = 0; r2 < 4; ++r2) xr[r2] = xpf[j][m][r2];
          }
#pragma unroll
          for (int r2 = 0; r2 < 4; ++r2)
            msgw[(d0 + r2) * 33 + jj * 16 + l16] =
                fmaxf(xr[r2] + pp * (acc2[m][j][r2] + cv4[m][r2]) + blv4[m][r2], 0.f);
        }
      }
      __syncthreads();   // D/F: msg ready
      for (int el = 0; el < 32; ++el) {
        int eg = h * 32 + el;
        runsum += msgw[lane * 33 + el];
        if (dst_lds[eg] != dst_lds[eg + 1]) {
          float* pdst = aggr + (long)dst_lds[eg] * DMODEL + d_own;
          const bool fin = (!have_next) && (eg == 63);  // block's final flush
          if (first_flush || fin) atomicAdd(pdst, runsum);
          else *pdst = runsum;   // interior dst: sole owner, complete sum
          first_flush = false;
          runsum = 0.f;
        }
      }
      __syncthreads();   // E/G: msg consumed (G also guards next-tile commit)
    }
  }
}

// ---------------------------------------------------------------------------
// node kernel, transposed; float4 I/O; in-register LN.
// ---------------------------------------------------------------------------
__global__ __launch_bounds__(256, 3)
void node_kernel(const float* __restrict__ x,
                 const float* __restrict__ aggr,
                 const ushort_t* __restrict__ Wg1bf,
                 const float* __restrict__ b_g1,
                 const float* __restrict__ ln_g,
                 const float* __restrict__ ln_b,
                 const ushort_t* __restrict__ Wg2bf,
                 const float* __restrict__ b_g2,
                 float* __restrict__ out) {
  __shared__ __align__(16) ushort_t a_lds[TILE_N * 264];
  __shared__ float ws_s[4][TILE_N];
  __shared__ float ws_ss[4][TILE_N];
  __shared__ float mu_lds[TILE_N], rs_lds[TILE_N];

  const int tid  = threadIdx.x;
  const int lane = tid & 63;
  const int wave = tid >> 6;
  const int l16  = lane & 15;
  const int quad = lane >> 4;
  const int dbase = wave * 64;
  const long nbase = (long)blockIdx.x * TILE_N;

#pragma unroll
  for (int i = 0; i < 16; ++i) {
    int id = tid + 256 * i;
    int r = id >> 6, c4 = (id & 63) * 4;
    long rr = nbase + r; if (rr >= N_NODES) rr = N_NODES - 1;
    floatx4 xv = ldf4(x + rr * DMODEL + c4);
    floatx4 av = ldf4(aggr + rr * DMODEL + c4);
    ushort4v pk = {f2bf(xv[0] + av[0]), f2bf(xv[1] + av[1]),
                   f2bf(xv[2] + av[2]), f2bf(xv[3] + av[3])};
    *(ushort4v*)(void*)(a_lds + r * 264 + c4) = pk;
  }
  __syncthreads();

  floatx4 acc[4][4];
#pragma unroll
  for (int m = 0; m < 4; ++m)
#pragma unroll
    for (int j = 0; j < 4; ++j) acc[m][j] = (floatx4){0.f, 0.f, 0.f, 0.f};
#pragma unroll
  for (int kt = 0; kt < 8; ++kt) {
    short8 aW[4], bN[4];
#pragma unroll
    for (int m = 0; m < 4; ++m)
      aW[m] = ldg16(Wg1bf + (dbase + m * 16 + l16) * DMODEL + kt * 32 + quad * 8);
#pragma unroll
    for (int j = 0; j < 4; ++j)
      bN[j] = *(const short8*)(const void*)(a_lds + (j * 16 + l16) * 264 + kt * 32 + quad * 8);
#pragma unroll
    for (int m = 0; m < 4; ++m)
#pragma unroll
      for (int j = 0; j < 4; ++j)
        acc[m][j] = __builtin_amdgcn_mfma_f32_16x16x32_bf16(aW[m], bN[j], acc[m][j], 0, 0, 0);
  }
#pragma unroll
  for (int m = 0; m < 4; ++m) {
    floatx4 bq = ldf4(b_g1 + dbase + m * 16 + quad * 4);
#pragma unroll
    for (int j = 0; j < 4; ++j)
#pragma unroll
      for (int r = 0; r < 4; ++r) acc[m][j][r] += bq[r];
  }

#pragma unroll
  for (int j = 0; j < 4; ++j) {
    float s = 0.f, ss = 0.f;
#pragma unroll
    for (int m = 0; m < 4; ++m)
#pragma unroll
      for (int r = 0; r < 4; ++r) { float v = acc[m][j][r]; s += v; ss += v * v; }
    s += __shfl_xor(s, 16); ss += __shfl_xor(ss, 16);
    s += __shfl_xor(s, 32); ss += __shfl_xor(ss, 32);
    if (quad == 0) { ws_s[wave][j * 16 + l16] = s; ws_ss[wave][j * 16 + l16] = ss; }
  }
  __syncthreads();
  if (tid < TILE_N) {
    float s = ws_s[0][tid] + ws_s[1][tid] + ws_s[2][tid] + ws_s[3][tid];
    float ss = ws_ss[0][tid] + ws_ss[1][tid] + ws_ss[2][tid] + ws_ss[3][tid];
    float mu = s * (1.f / 256.f);
    float var = ss * (1.f / 256.f) - mu * mu;
    mu_lds[tid] = mu;
    rs_lds[tid] = rsqrtf(var + 1e-5f);
  }
  __syncthreads();

#pragma unroll
  for (int m = 0; m < 4; ++m) {
    int d0 = dbase + m * 16 + quad * 4;
    floatx4 lg = ldf4(ln_g + d0), lb = ldf4(ln_b + d0);
#pragma unroll
    for (int j = 0; j < 4; ++j) {
      int e = j * 16 + l16;
      float mu = mu_lds[e], rs = rs_lds[e];
      ushort4v pk = {f2bf(fmaxf((acc[m][j][0] - mu) * rs * lg[0] + lb[0], 0.f)),
                     f2bf(fmaxf((acc[m][j][1] - mu) * rs * lg[1] + lb[1], 0.f)),
                     f2bf(fmaxf((acc[m][j][2] - mu) * rs * lg[2] + lb[2], 0.f)),
                     f2bf(fmaxf((acc[m][j][3] - mu) * rs * lg[3] + lb[3], 0.f))};
      *(ushort4v*)(void*)(a_lds + e * 264 + d0) = pk;
    }
  }
  __syncthreads();

#pragma unroll
  for (int m = 0; m < 4; ++m)
#pragma unroll
    for (int j = 0; j < 4; ++j) acc[m][j] = (floatx4){0.f, 0.f, 0.f, 0.f};
#pragma unroll
  for (int kt = 0; kt < 8; ++kt) {
    short8 aW[4], bN[4];
#pragma unroll
    for (int m = 0; m < 4; ++m)
      aW[m] = ldg16(Wg2bf + (dbase + m * 16 + l16) * DMODEL + kt * 32 + quad * 8);
#pragma unroll
    for (int j = 0; j < 4; ++j)
      bN[j] = *(const short8*)(const void*)(a_lds + (j * 16 + l16) * 264 + kt * 32 + quad * 8);
#pragma unroll
    for (int m = 0; m < 4; ++m)
#pragma unroll
      for (int j = 0; j < 4; ++j)
        acc[m][j] = __builtin_amdgcn_mfma_f32_16x16x32_bf16(aW[m], bN[j], acc[m][j], 0, 0, 0);
  }
#pragma unroll
  for (int m = 0; m < 4; ++m) {
    int d0 = dbase + m * 16 + quad * 4;
    floatx4 bq = ldf4(b_g2 + d0);
#pragma unroll
    for (int j = 0; j < 4; ++j) {
      long row = nbase + j * 16 + l16;
      if (row < N_NODES) {
        floatx4 o = {acc[m][j][0] + bq[0], acc[m][j][1] + bq[1],
                     acc[m][j][2] + bq[2], acc[m][j][3] + bq[3]};
        *(floatx4*)(void*)(out + row * DMODEL + d0) = o;
      }
    }
  }
}

// ---------------------------------------------------------------------------
extern "C" void kernel_launch(void* const* d_in, const int* in_sizes, int n_in,
                              void* d_out, int out_size, void* d_ws, size_t ws_size,
                              hipStream_t stream) {
  const float* x     = (const float*)d_in[0];
  const int*   eidx  = (const int*)d_in[1];
  const float* eattr = (const float*)d_in[2];
  const float* W_e1  = (const float*)d_in[3];
  const float* b_e1  = (const float*)d_in[4];
  const float* W_e2  = (const float*)d_in[5];
  const float* b_e2  = (const float*)d_in[6];
  const float* W_le  = (const float*)d_in[7];
  const float* b_le  = (const float*)d_in[8];
  const float* W_g1  = (const float*)d_in[9];
  const float* b_g1  = (const float*)d_in[10];
  const float* ln_g  = (const float*)d_in[11];
  const float* ln_b  = (const float*)d_in[12];
  const float* W_g2  = (const float*)d_in[13];
  const float* b_g2  = (const float*)d_in[14];
  float* out = (float*)d_out;

  char* ws = (char*)d_ws;
  ushort_t* Mw     = (ushort_t*)(ws);                 // 131072
  ushort_t* Wg1bf  = (ushort_t*)(ws + 131072);        // 131072
  ushort_t* Wg2bf  = (ushort_t*)(ws + 262144);        // 131072
  ushort_t* We1bf  = (ushort_t*)(ws + 393216);        // 32768
  float*    cw     = (float*)   (ws + 425984);        // 1024
  float*    aggr   = (float*)   (ws + 427008);        // 51,200,000
  int*      counts = (int*)     (ws + 51627008);      // 200,000
  int*      cur    = (int*)     (ws + 51827008);      // 200,000
  int*      perm   = (int*)     (ws + 52027008);      // 3,200,000
  int*      bsum   = (int*)     (ws + 55227008);      // 1,024
  int*      bofs   = (int*)     (ws + 55228032);      // 1,024
  ushort_t* xbf    = (ushort_t*)(ws + 55229056);      // 25,600,000 -> 80,829,056
  const size_t NEED_BF = 80829056;
  const bool use_bf = (ws_size >= NEED_BF);

  hipMemsetAsync(aggr, 0, (size_t)N_NODES * DMODEL * sizeof(float), stream);
  hipMemsetAsync(counts, 0, (size_t)N_NODES * sizeof(int), stream);
  prep_kernel<<<dim3(DMODEL), dim3(DMODEL), 0, stream>>>(
      W_le, W_e2, b_e2, W_e1, W_g1, W_g2, Mw, cw, We1bf, Wg1bf, Wg2bf);
  if (use_bf)
    xconv_kernel<<<dim3(N_NODES * DMODEL / 4 / 256), dim3(256), 0, stream>>>(x, xbf);
  hist_kernel<<<dim3((N_EDGES + 255) / 256), dim3(256), 0, stream>>>(eidx, counts);
  scan_block_kernel<<<dim3(NB_SCAN), dim3(256), 0, stream>>>(counts, cur, bsum);
  scan_total_kernel<<<dim3(1), dim3(256), 0, stream>>>(bsum, bofs);
  scan_add_kernel<<<dim3(NB_SCAN), dim3(256), 0, stream>>>(cur, bofs);
  scatter_kernel<<<dim3((N_EDGES + 255) / 256), dim3(256), 0, stream>>>(eidx, cur, perm);
  if (use_bf)
    edge_kernel<true><<<dim3(NBLK_EDGE), dim3(256), 0, stream>>>(
        x, xbf, eidx, eattr, perm, We1bf, b_e1, b_le, Mw, cw, aggr);
  else
    edge_kernel<false><<<dim3(NBLK_EDGE), dim3(256), 0, stream>>>(
        x, xbf, eidx, eattr, perm, We1bf, b_e1, b_le, Mw, cw, aggr);
  node_kernel<<<dim3(N_NTILES), dim3(256), 0, stream>>>(
      x, aggr, Wg1bf, b_g1, ln_g, ln_b, Wg2bf, b_g2, out);
}

// Round 7
// 1101.929 us; speedup vs baseline: 1.1415x; 1.1415x over previous
//
#include <hip/hip_runtime.h>
#include <stdint.h>

#define N_NODES 50000
#define N_EDGES 800000
#define DMODEL  256
#define FEDGE   64
#define TILE_E  64
#define N_ETILES (N_EDGES / TILE_E)   // 12500
#define NBLK_EDGE 768                 // persistent blocks: 3 blocks/CU on 256 CUs
#define TILE_N  64
#define N_NTILES ((N_NODES + TILE_N - 1) / TILE_N)  // 782
#define NB_SCAN ((N_NODES + 255) / 256)             // 196

typedef short short8 __attribute__((ext_vector_type(8)));
typedef float floatx4 __attribute__((ext_vector_type(4)));
typedef unsigned short ushort_t;
typedef unsigned short ushort4v __attribute__((ext_vector_type(4)));

__device__ __forceinline__ ushort_t f2bf(float f) {
  union { float f; unsigned int i; } v; v.f = f;
  unsigned int x = v.i;
  unsigned int r = x + 0x7fffu + ((x >> 16) & 1u);  // RNE
  return (ushort_t)(r >> 16);
}
__device__ __forceinline__ float bf2f(ushort_t u) {
  union { unsigned int i; float f; } v; v.i = ((unsigned int)u) << 16; return v.f;
}
__device__ __forceinline__ short8 ldg16(const ushort_t* p) {
  return *(const short8*)(const void*)p;
}
__device__ __forceinline__ floatx4 ldf4(const float* p) {
  return *(const floatx4*)(const void*)p;
}

// ---------------------------------------------------------------------------
// prep: M = bf16(W_le @ W_e2), c = W_le @ b_e2 (f32); bf16 copies of weights.
// ---------------------------------------------------------------------------
__global__ void prep_kernel(const float* __restrict__ W_le,
                            const float* __restrict__ W_e2,
                            const float* __restrict__ b_e2,
                            const float* __restrict__ W_e1,
                            const float* __restrict__ W_g1,
                            const float* __restrict__ W_g2,
                            ushort_t* __restrict__ Mw, float* __restrict__ cw,
                            ushort_t* __restrict__ We1bf,
                            ushort_t* __restrict__ Wg1bf,
                            ushort_t* __restrict__ Wg2bf) {
  int d = blockIdx.x, k = threadIdx.x;
  float acc = 0.f;
  for (int j = 0; j < DMODEL; ++j)
    acc += W_le[d * DMODEL + j] * W_e2[j * DMODEL + k];
  Mw[d * DMODEL + k] = f2bf(acc);
  Wg1bf[d * DMODEL + k] = f2bf(W_g1[d * DMODEL + k]);
  Wg2bf[d * DMODEL + k] = f2bf(W_g2[d * DMODEL + k]);
  if (k < FEDGE) We1bf[d * FEDGE + k] = f2bf(W_e1[d * FEDGE + k]);
  if (k == 0) {
    float cc = 0.f;
    for (int j = 0; j < DMODEL; ++j) cc += W_le[d * DMODEL + j] * b_e2[j];
    cw[d] = cc;
  }
}

// x -> bf16 copy (makes the edge gather 2B/elem and L3-resident: 25.6 MB)
__global__ void xconv_kernel(const float* __restrict__ x, ushort_t* __restrict__ xbf) {
  int i = blockIdx.x * blockDim.x + threadIdx.x;   // one float4 per thread
  floatx4 v = ldf4(x + (long)i * 4);
  ushort4v pk = {f2bf(v[0]), f2bf(v[1]), f2bf(v[2]), f2bf(v[3])};
  *(ushort4v*)(void*)(xbf + (long)i * 4) = pk;
}

// ---------------------------------------------------------------------------
// counting sort by dst: histogram -> 3-phase shfl scan -> scatter(perm)
// ---------------------------------------------------------------------------
__global__ void hist_kernel(const int* __restrict__ eidx, int* __restrict__ counts) {
  int e = blockIdx.x * blockDim.x + threadIdx.x;
  if (e < N_EDGES) atomicAdd(counts + eidx[N_EDGES + e], 1);
}

__global__ void scan_block_kernel(const int* __restrict__ counts,
                                  int* __restrict__ cur, int* __restrict__ bsum) {
  __shared__ int wsum[4];
  int i = blockIdx.x * 256 + threadIdx.x;
  int lane = threadIdx.x & 63, wave = threadIdx.x >> 6;
  int v = (i < N_NODES) ? counts[i] : 0;
  int s = v;
#pragma unroll
  for (int off = 1; off <= 32; off <<= 1) {
    int t = __shfl_up(s, off);
    if (lane >= off) s += t;
  }
  if (lane == 63) wsum[wave] = s;
  __syncthreads();
  int woff = 0;
  if (wave > 0) woff += wsum[0];
  if (wave > 1) woff += wsum[1];
  if (wave > 2) woff += wsum[2];
  if (i < N_NODES) cur[i] = s - v + woff;            // block-local exclusive
  if (threadIdx.x == 255) bsum[blockIdx.x] = s + woff;
}

__global__ void scan_total_kernel(const int* __restrict__ bsum, int* __restrict__ bofs) {
  __shared__ int wsum[4];
  int tid = threadIdx.x;
  int lane = tid & 63, wave = tid >> 6;
  int v = (tid < NB_SCAN) ? bsum[tid] : 0;
  int s = v;
#pragma unroll
  for (int off = 1; off <= 32; off <<= 1) {
    int t = __shfl_up(s, off);
    if (lane >= off) s += t;
  }
  if (lane == 63) wsum[wave] = s;
  __syncthreads();
  int woff = 0;
  if (wave > 0) woff += wsum[0];
  if (wave > 1) woff += wsum[1];
  if (wave > 2) woff += wsum[2];
  if (tid < NB_SCAN) bofs[tid] = s - v + woff;
}

__global__ void scan_add_kernel(int* __restrict__ cur, const int* __restrict__ bofs) {
  int i = blockIdx.x * 256 + threadIdx.x;
  if (i < N_NODES) cur[i] += bofs[i >> 8];
}

__global__ void scatter_kernel(const int* __restrict__ eidx, int* __restrict__ cur,
                               int* __restrict__ perm) {
  int e = blockIdx.x * blockDim.x + threadIdx.x;
  if (e < N_EDGES) {
    int d = eidx[N_EDGES + e];
    int pos = atomicAdd(cur + d, 1);
    perm[pos] = e;
  }
}

// ---------------------------------------------------------------------------
// staging helpers for the persistent edge kernel (registers only, no LDS)
// ---------------------------------------------------------------------------
__device__ __forceinline__ void load_tile_ptrs(long ebase, int tid,
                                               const int* __restrict__ perm,
                                               int (&pe4)[4], int& pe1) {
  int r0 = tid >> 4;
#pragma unroll
  for (int p = 0; p < 4; ++p) pe4[p] = perm[ebase + p * 16 + r0];
  if (tid < TILE_E) pe1 = perm[ebase + tid];
}

__device__ __forceinline__ void load_tile_data(int tid, const int (&pe4)[4], int pe1,
                                               const float* __restrict__ eattr,
                                               const int* __restrict__ eidx,
                                               ushort4v (&rawreg)[4], float& polreg,
                                               int& srcreg, int& dstreg) {
  int c = (tid & 15) * 4;
#pragma unroll
  for (int p = 0; p < 4; ++p) {
    const float* sp = eattr + (long)pe4[p] * 65 + 1 + c;
    rawreg[p] = (ushort4v){f2bf(sp[0]), f2bf(sp[1]), f2bf(sp[2]), f2bf(sp[3])};
  }
  if (tid < TILE_E) {
    polreg = eattr[(long)pe1 * 65];
    srcreg = eidx[pe1];
    dstreg = eidx[N_EDGES + pe1];
  }
}

// ---------------------------------------------------------------------------
// edge kernel: persistent blocks (3/CU), XCD-chunked contiguous tile ranges,
// carry-across-tiles one-shot aggr flush (store for interior dsts, atomic at
// the two chunk-boundary flushes).
// THIS ROUND: x[src] fragments are loaded JUST-IN-TIME inside the epilogue
// (after barrier C), never co-live with GEMM2's acc2 -> peak VGPR pressure
// drops below the allocator's spill threshold. R4-R6 counters showed ~400 MB
// of symmetric FETCH+WRITE scratch-spill traffic (VGPR collapsed 128->84 the
// round the prefetch became live across GEMM2; traffic was insensitive to
// every aggr-policy change).
// ---------------------------------------------------------------------------
template <bool USEBF>
__global__ __launch_bounds__(256, 3)
void edge_kernel(const float* __restrict__ x,
                 const ushort_t* __restrict__ xbf,
                 const int* __restrict__ eidx,
                 const float* __restrict__ eattr,
                 const int* __restrict__ perm,
                 const ushort_t* __restrict__ We1bf,
                 const float* __restrict__ b_e1,
                 const float* __restrict__ b_le,
                 const ushort_t* __restrict__ Mw,
                 const float* __restrict__ cw,
                 float* __restrict__ aggr) {
  __shared__ __align__(16) ushort_t raw_lds[TILE_E * 72];
  __shared__ __align__(16) ushort_t t1_lds[TILE_E * 264];  // reused as msg f32
  __shared__ float pp_lds[TILE_E];
  __shared__ int src_lds[TILE_E];
  __shared__ int dst_lds[TILE_E + 1];

  const int tid  = threadIdx.x;
  const int lane = tid & 63;
  const int wave = tid >> 6;
  const int l16  = lane & 15;
  const int quad = lane >> 4;
  const int dbase = wave * 64;
  const int d_own = dbase + lane;

  // XCD-chunked, balanced tile range (bijective: 768 = 8 XCDs x 96)
  const int pb = blockIdx.x;
  const int lb = (pb & 7) * (NBLK_EDGE / 8) + (pb >> 3);
  const int q  = N_ETILES / NBLK_EDGE;                  // 16
  const int r  = N_ETILES % NBLK_EDGE;                  // 212
  const long tbeg = (long)lb * q + (lb < r ? lb : r);
  const long tend = tbeg + q + (lb < r ? 1 : 0);

  // prologue: stage first tile into registers
  int pe4[4], pe1 = 0;
  ushort4v rawreg[4];
  float polreg = 0.f;
  int srcreg = 0, dstreg = 0;
  load_tile_ptrs(tbeg * TILE_E, tid, perm, pe4, pe1);
  load_tile_data(tid, pe4, pe1, eattr, eidx, rawreg, polreg, srcreg, dstreg);

  float runsum = 0.f;        // carries across halves AND tiles
  bool first_flush = true;   // block's first flush -> atomic (shared boundary)

  for (long t = tbeg; t < tend; ++t) {
    const long tn = t + 1;
    const bool have_next = (tn < tend);

    // issue next tile's perm-pointer loads FIRST (covered by commit+A+GEMM1)
    if (have_next) load_tile_ptrs(tn * TILE_E, tid, perm, pe4, pe1);

    // ---- commit staged registers to LDS (current tile t)
    {
      int r0 = tid >> 4, c = (tid & 15) * 4;
#pragma unroll
      for (int p = 0; p < 4; ++p)
        *(ushort4v*)(void*)(raw_lds + (p * 16 + r0) * 72 + c) = rawreg[p];
      if (tid < TILE_E) {
        pp_lds[tid] = fminf(fmaxf(polreg, 0.f), 1.f) + 0.01f;
        src_lds[tid] = srcreg;
        dst_lds[tid] = dstreg;
      }
    }
    __syncthreads();   // A: staging visible

    // GEMM1 (transposed): t1^T[f][e]
    {
      floatx4 acc1[4][4];
#pragma unroll
      for (int m = 0; m < 4; ++m)
#pragma unroll
        for (int j = 0; j < 4; ++j) acc1[m][j] = (floatx4){0.f, 0.f, 0.f, 0.f};
#pragma unroll
      for (int kt = 0; kt < 2; ++kt) {
        short8 aW[4], bE[4];
#pragma unroll
        for (int m = 0; m < 4; ++m)
          aW[m] = ldg16(We1bf + (dbase + m * 16 + l16) * FEDGE + kt * 32 + quad * 8);
#pragma unroll
        for (int j = 0; j < 4; ++j)
          bE[j] = *(const short8*)(const void*)(raw_lds + (j * 16 + l16) * 72 + kt * 32 + quad * 8);
#pragma unroll
        for (int m = 0; m < 4; ++m)
#pragma unroll
          for (int j = 0; j < 4; ++j)
            acc1[m][j] = __builtin_amdgcn_mfma_f32_16x16x32_bf16(aW[m], bE[j], acc1[m][j], 0, 0, 0);
      }
#pragma unroll
      for (int m = 0; m < 4; ++m) {
        int f0 = dbase + m * 16 + quad * 4;
        floatx4 be1q = ldf4(b_e1 + f0);
#pragma unroll
        for (int j = 0; j < 4; ++j) {
          int e = j * 16 + l16;
          ushort4v pk = {f2bf(fmaxf(acc1[m][j][0] + be1q[0], 0.f)),
                         f2bf(fmaxf(acc1[m][j][1] + be1q[1], 0.f)),
                         f2bf(fmaxf(acc1[m][j][2] + be1q[2], 0.f)),
                         f2bf(fmaxf(acc1[m][j][3] + be1q[3], 0.f))};
          *(ushort4v*)(void*)(t1_lds + e * 264 + f0) = pk;
        }
      }
    }
    __syncthreads();   // B: t1 ready (acc1 dead here)

    // issue next tile's dependent gathers (covered by GEMM2)
    if (have_next)
      load_tile_data(tid, pe4, pe1, eattr, eidx, rawreg, polreg, srcreg, dstreg);

    // GEMM2 (transposed): pre^T[d][e]
    floatx4 acc2[4][4];
#pragma unroll
    for (int m = 0; m < 4; ++m)
#pragma unroll
      for (int j = 0; j < 4; ++j) acc2[m][j] = (floatx4){0.f, 0.f, 0.f, 0.f};
#pragma unroll
    for (int kt = 0; kt < 8; ++kt) {
      short8 aW[4], bE[4];
#pragma unroll
      for (int m = 0; m < 4; ++m)
        aW[m] = ldg16(Mw + (dbase + m * 16 + l16) * DMODEL + kt * 32 + quad * 8);
#pragma unroll
      for (int j = 0; j < 4; ++j)
        bE[j] = *(const short8*)(const void*)(t1_lds + (j * 16 + l16) * 264 + kt * 32 + quad * 8);
#pragma unroll
      for (int m = 0; m < 4; ++m)
#pragma unroll
        for (int j = 0; j < 4; ++j)
          acc2[m][j] = __builtin_amdgcn_mfma_f32_16x16x32_bf16(aW[m], bE[j], acc2[m][j], 0, 0, 0);
    }
    __syncthreads();   // C: t1 dead; LDS reused as per-wave msg buffer

    // publish next tile's first dst into the carry slot (read after barrier D/F)
    if (tid == 0) dst_lds[TILE_E] = have_next ? dstreg : -9;

    // JIT x[src] fragment loads: issued here (after C), consumed below.
    // Short live range -> never co-live with GEMM2 -> no spill.
    ushort4v xq[4][4];
    floatx4  xqf[4][4];
#pragma unroll
    for (int j = 0; j < 4; ++j) {
      long srow = (long)src_lds[j * 16 + l16] * DMODEL;
#pragma unroll
      for (int m = 0; m < 4; ++m) {
        int d0 = dbase + m * 16 + quad * 4;
        if constexpr (USEBF)
          xq[j][m] = *(const ushort4v*)(const void*)(xbf + srow + d0);
        else
          xqf[j][m] = ldf4(x + srow + d0);
      }
    }

    floatx4 cv4[4], blv4[4];
#pragma unroll
    for (int m = 0; m < 4; ++m) {
      int d0 = dbase + m * 16 + quad * 4;
      cv4[m] = ldf4(cw + d0);
      blv4[m] = ldf4(b_le + d0);
    }
    float* msgw = ((float*)(void*)t1_lds) + wave * (64 * 33);

#pragma unroll
    for (int h = 0; h < 2; ++h) {
#pragma unroll
      for (int jj = 0; jj < 2; ++jj) {
        int j = h * 2 + jj;
        int e = j * 16 + l16;
        float pp = pp_lds[e];
#pragma unroll
        for (int m = 0; m < 4; ++m) {
          int d0 = m * 16 + quad * 4;
          float xr[4];
          if constexpr (USEBF) {
#pragma unroll
            for (int r2 = 0; r2 < 4; ++r2) xr[r2] = bf2f(xq[j][m][r2]);
          } else {
#pragma unroll
            for (int r2 = 0; r2 < 4; ++r2) xr[r2] = xqf[j][m][r2];
          }
#pragma unroll
          for (int r2 = 0; r2 < 4; ++r2)
            msgw[(d0 + r2) * 33 + jj * 16 + l16] =
                fmaxf(xr[r2] + pp * (acc2[m][j][r2] + cv4[m][r2]) + blv4[m][r2], 0.f);
        }
      }
      __syncthreads();   // D/F: msg ready
      for (int el = 0; el < 32; ++el) {
        int eg = h * 32 + el;
        runsum += msgw[lane * 33 + el];
        if (dst_lds[eg] != dst_lds[eg + 1]) {
          float* pdst = aggr + (long)dst_lds[eg] * DMODEL + d_own;
          const bool fin = (!have_next) && (eg == 63);  // block's final flush
          if (first_flush || fin) atomicAdd(pdst, runsum);
          else *pdst = runsum;   // interior dst: sole owner, complete sum
          first_flush = false;
          runsum = 0.f;
        }
      }
      __syncthreads();   // E/G: msg consumed (G also guards next-tile commit)
    }
  }
}

// ---------------------------------------------------------------------------
// node kernel, transposed; float4 I/O; in-register LN.
// ---------------------------------------------------------------------------
__global__ __launch_bounds__(256, 3)
void node_kernel(const float* __restrict__ x,
                 const float* __restrict__ aggr,
                 const ushort_t* __restrict__ Wg1bf,
                 const float* __restrict__ b_g1,
                 const float* __restrict__ ln_g,
                 const float* __restrict__ ln_b,
                 const ushort_t* __restrict__ Wg2bf,
                 const float* __restrict__ b_g2,
                 float* __restrict__ out) {
  __shared__ __align__(16) ushort_t a_lds[TILE_N * 264];
  __shared__ float ws_s[4][TILE_N];
  __shared__ float ws_ss[4][TILE_N];
  __shared__ float mu_lds[TILE_N], rs_lds[TILE_N];

  const int tid  = threadIdx.x;
  const int lane = tid & 63;
  const int wave = tid >> 6;
  const int l16  = lane & 15;
  const int quad = lane >> 4;
  const int dbase = wave * 64;
  const long nbase = (long)blockIdx.x * TILE_N;

#pragma unroll
  for (int i = 0; i < 16; ++i) {
    int id = tid + 256 * i;
    int r = id >> 6, c4 = (id & 63) * 4;
    long rr = nbase + r; if (rr >= N_NODES) rr = N_NODES - 1;
    floatx4 xv = ldf4(x + rr * DMODEL + c4);
    floatx4 av = ldf4(aggr + rr * DMODEL + c4);
    ushort4v pk = {f2bf(xv[0] + av[0]), f2bf(xv[1] + av[1]),
                   f2bf(xv[2] + av[2]), f2bf(xv[3] + av[3])};
    *(ushort4v*)(void*)(a_lds + r * 264 + c4) = pk;
  }
  __syncthreads();

  floatx4 acc[4][4];
#pragma unroll
  for (int m = 0; m < 4; ++m)
#pragma unroll
    for (int j = 0; j < 4; ++j) acc[m][j] = (floatx4){0.f, 0.f, 0.f, 0.f};
#pragma unroll
  for (int kt = 0; kt < 8; ++kt) {
    short8 aW[4], bN[4];
#pragma unroll
    for (int m = 0; m < 4; ++m)
      aW[m] = ldg16(Wg1bf + (dbase + m * 16 + l16) * DMODEL + kt * 32 + quad * 8);
#pragma unroll
    for (int j = 0; j < 4; ++j)
      bN[j] = *(const short8*)(const void*)(a_lds + (j * 16 + l16) * 264 + kt * 32 + quad * 8);
#pragma unroll
    for (int m = 0; m < 4; ++m)
#pragma unroll
      for (int j = 0; j < 4; ++j)
        acc[m][j] = __builtin_amdgcn_mfma_f32_16x16x32_bf16(aW[m], bN[j], acc[m][j], 0, 0, 0);
  }
#pragma unroll
  for (int m = 0; m < 4; ++m) {
    floatx4 bq = ldf4(b_g1 + dbase + m * 16 + quad * 4);
#pragma unroll
    for (int j = 0; j < 4; ++j)
#pragma unroll
      for (int r = 0; r < 4; ++r) acc[m][j][r] += bq[r];
  }

#pragma unroll
  for (int j = 0; j < 4; ++j) {
    float s = 0.f, ss = 0.f;
#pragma unroll
    for (int m = 0; m < 4; ++m)
#pragma unroll
      for (int r = 0; r < 4; ++r) { float v = acc[m][j][r]; s += v; ss += v * v; }
    s += __shfl_xor(s, 16); ss += __shfl_xor(ss, 16);
    s += __shfl_xor(s, 32); ss += __shfl_xor(ss, 32);
    if (quad == 0) { ws_s[wave][j * 16 + l16] = s; ws_ss[wave][j * 16 + l16] = ss; }
  }
  __syncthreads();
  if (tid < TILE_N) {
    float s = ws_s[0][tid] + ws_s[1][tid] + ws_s[2][tid] + ws_s[3][tid];
    float ss = ws_ss[0][tid] + ws_ss[1][tid] + ws_ss[2][tid] + ws_ss[3][tid];
    float mu = s * (1.f / 256.f);
    float var = ss * (1.f / 256.f) - mu * mu;
    mu_lds[tid] = mu;
    rs_lds[tid] = rsqrtf(var + 1e-5f);
  }
  __syncthreads();

#pragma unroll
  for (int m = 0; m < 4; ++m) {
    int d0 = dbase + m * 16 + quad * 4;
    floatx4 lg = ldf4(ln_g + d0), lb = ldf4(ln_b + d0);
#pragma unroll
    for (int j = 0; j < 4; ++j) {
      int e = j * 16 + l16;
      float mu = mu_lds[e], rs = rs_lds[e];
      ushort4v pk = {f2bf(fmaxf((acc[m][j][0] - mu) * rs * lg[0] + lb[0], 0.f)),
                     f2bf(fmaxf((acc[m][j][1] - mu) * rs * lg[1] + lb[1], 0.f)),
                     f2bf(fmaxf((acc[m][j][2] - mu) * rs * lg[2] + lb[2], 0.f)),
                     f2bf(fmaxf((acc[m][j][3] - mu) * rs * lg[3] + lb[3], 0.f))};
      *(ushort4v*)(void*)(a_lds + e * 264 + d0) = pk;
    }
  }
  __syncthreads();

#pragma unroll
  for (int m = 0; m < 4; ++m)
#pragma unroll
    for (int j = 0; j < 4; ++j) acc[m][j] = (floatx4){0.f, 0.f, 0.f, 0.f};
#pragma unroll
  for (int kt = 0; kt < 8; ++kt) {
    short8 aW[4], bN[4];
#pragma unroll
    for (int m = 0; m < 4; ++m)
      aW[m] = ldg16(Wg2bf + (dbase + m * 16 + l16) * DMODEL + kt * 32 + quad * 8);
#pragma unroll
    for (int j = 0; j < 4; ++j)
      bN[j] = *(const short8*)(const void*)(a_lds + (j * 16 + l16) * 264 + kt * 32 + quad * 8);
#pragma unroll
    for (int m = 0; m < 4; ++m)
#pragma unroll
      for (int j = 0; j < 4; ++j)
        acc[m][j] = __builtin_amdgcn_mfma_f32_16x16x32_bf16(aW[m], bN[j], acc[m][j], 0, 0, 0);
  }
#pragma unroll
  for (int m = 0; m < 4; ++m) {
    int d0 = dbase + m * 16 + quad * 4;
    floatx4 bq = ldf4(b_g2 + d0);
#pragma unroll
    for (int j = 0; j < 4; ++j) {
      long row = nbase + j * 16 + l16;
      if (row < N_NODES) {
        floatx4 o = {acc[m][j][0] + bq[0], acc[m][j][1] + bq[1],
                     acc[m][j][2] + bq[2], acc[m][j][3] + bq[3]};
        *(floatx4*)(void*)(out + row * DMODEL + d0) = o;
      }
    }
  }
}

// ---------------------------------------------------------------------------
extern "C" void kernel_launch(void* const* d_in, const int* in_sizes, int n_in,
                              void* d_out, int out_size, void* d_ws, size_t ws_size,
                              hipStream_t stream) {
  const float* x     = (const float*)d_in[0];
  const int*   eidx  = (const int*)d_in[1];
  const float* eattr = (const float*)d_in[2];
  const float* W_e1  = (const float*)d_in[3];
  const float* b_e1  = (const float*)d_in[4];
  const float* W_e2  = (const float*)d_in[5];
  const float* b_e2  = (const float*)d_in[6];
  const float* W_le  = (const float*)d_in[7];
  const float* b_le  = (const float*)d_in[8];
  const float* W_g1  = (const float*)d_in[9];
  const float* b_g1  = (const float*)d_in[10];
  const float* ln_g  = (const float*)d_in[11];
  const float* ln_b  = (const float*)d_in[12];
  const float* W_g2  = (const float*)d_in[13];
  const float* b_g2  = (const float*)d_in[14];
  float* out = (float*)d_out;

  char* ws = (char*)d_ws;
  ushort_t* Mw     = (ushort_t*)(ws);                 // 131072
  ushort_t* Wg1bf  = (ushort_t*)(ws + 131072);        // 131072
  ushort_t* Wg2bf  = (ushort_t*)(ws + 262144);        // 131072
  ushort_t* We1bf  = (ushort_t*)(ws + 393216);        // 32768
  float*    cw     = (float*)   (ws + 425984);        // 1024
  float*    aggr   = (float*)   (ws + 427008);        // 51,200,000
  int*      counts = (int*)     (ws + 51627008);      // 200,000
  int*      cur    = (int*)     (ws + 51827008);      // 200,000
  int*      perm   = (int*)     (ws + 52027008);      // 3,200,000
  int*      bsum   = (int*)     (ws + 55227008);      // 1,024
  int*      bofs   = (int*)     (ws + 55228032);      // 1,024
  ushort_t* xbf    = (ushort_t*)(ws + 55229056);      // 25,600,000 -> 80,829,056
  const size_t NEED_BF = 80829056;
  const bool use_bf = (ws_size >= NEED_BF);

  hipMemsetAsync(aggr, 0, (size_t)N_NODES * DMODEL * sizeof(float), stream);
  hipMemsetAsync(counts, 0, (size_t)N_NODES * sizeof(int), stream);
  prep_kernel<<<dim3(DMODEL), dim3(DMODEL), 0, stream>>>(
      W_le, W_e2, b_e2, W_e1, W_g1, W_g2, Mw, cw, We1bf, Wg1bf, Wg2bf);
  if (use_bf)
    xconv_kernel<<<dim3(N_NODES * DMODEL / 4 / 256), dim3(256), 0, stream>>>(x, xbf);
  hist_kernel<<<dim3((N_EDGES + 255) / 256), dim3(256), 0, stream>>>(eidx, counts);
  scan_block_kernel<<<dim3(NB_SCAN), dim3(256), 0, stream>>>(counts, cur, bsum);
  scan_total_kernel<<<dim3(1), dim3(256), 0, stream>>>(bsum, bofs);
  scan_add_kernel<<<dim3(NB_SCAN), dim3(256), 0, stream>>>(cur, bofs);
  scatter_kernel<<<dim3((N_EDGES + 255) / 256), dim3(256), 0, stream>>>(eidx, cur, perm);
  if (use_bf)
    edge_kernel<true><<<dim3(NBLK_EDGE), dim3(256), 0, stream>>>(
        x, xbf, eidx, eattr, perm, We1bf, b_e1, b_le, Mw, cw, aggr);
  else
    edge_kernel<false><<<dim3(NBLK_EDGE), dim3(256), 0, stream>>>(
        x, xbf, eidx, eattr, perm, We1bf, b_e1, b_le, Mw, cw, aggr);
  node_kernel<<<dim3(N_NTILES), dim3(256), 0, stream>>>(
      x, aggr, Wg1bf, b_g1, ln_g, ln_b, Wg2bf, b_g2, out);
}

// Round 12
// 1095.062 us; speedup vs baseline: 1.1487x; 1.0063x over previous
//
#include <hip/hip_runtime.h>
#include <stdint.h>

#define N_NODES 50000
#define N_EDGES 800000
#define DMODEL  256
#define FEDGE   64
#define TILE_E  64
#define N_ETILES (N_EDGES / TILE_E)   // 12500
#define NBLK_EDGE 768                 // persistent blocks: 3 blocks/CU on 256 CUs
#define TILE_N  64
#define N_NTILES ((N_NODES + TILE_N - 1) / TILE_N)  // 782
#define NB_SCAN ((N_NODES + 255) / 256)             // 196

typedef short short8 __attribute__((ext_vector_type(8)));
typedef float floatx4 __attribute__((ext_vector_type(4)));
typedef unsigned short ushort_t;
typedef unsigned short ushort4v __attribute__((ext_vector_type(4)));

__device__ __forceinline__ ushort_t f2bf(float f) {
  union { float f; unsigned int i; } v; v.f = f;
  unsigned int x = v.i;
  unsigned int r = x + 0x7fffu + ((x >> 16) & 1u);  // RNE
  return (ushort_t)(r >> 16);
}
__device__ __forceinline__ float bf2f(ushort_t u) {
  union { unsigned int i; float f; } v; v.i = ((unsigned int)u) << 16; return v.f;
}
__device__ __forceinline__ short8 ldg16(const ushort_t* p) {
  return *(const short8*)(const void*)p;
}
__device__ __forceinline__ floatx4 ldf4(const float* p) {
  return *(const floatx4*)(const void*)p;
}

// ---------------------------------------------------------------------------
// prep: M = bf16(W_le @ W_e2), c = W_le @ b_e2 (f32); bf16 copies of weights.
// ---------------------------------------------------------------------------
__global__ void prep_kernel(const float* __restrict__ W_le,
                            const float* __restrict__ W_e2,
                            const float* __restrict__ b_e2,
                            const float* __restrict__ W_e1,
                            const float* __restrict__ W_g1,
                            const float* __restrict__ W_g2,
                            ushort_t* __restrict__ Mw, float* __restrict__ cw,
                            ushort_t* __restrict__ We1bf,
                            ushort_t* __restrict__ Wg1bf,
                            ushort_t* __restrict__ Wg2bf) {
  int d = blockIdx.x, k = threadIdx.x;
  float acc = 0.f;
  for (int j = 0; j < DMODEL; ++j)
    acc += W_le[d * DMODEL + j] * W_e2[j * DMODEL + k];
  Mw[d * DMODEL + k] = f2bf(acc);
  Wg1bf[d * DMODEL + k] = f2bf(W_g1[d * DMODEL + k]);
  Wg2bf[d * DMODEL + k] = f2bf(W_g2[d * DMODEL + k]);
  if (k < FEDGE) We1bf[d * FEDGE + k] = f2bf(W_e1[d * FEDGE + k]);
  if (k == 0) {
    float cc = 0.f;
    for (int j = 0; j < DMODEL; ++j) cc += W_le[d * DMODEL + j] * b_e2[j];
    cw[d] = cc;
  }
}

// x -> bf16 copy (makes the edge gather 2B/elem and L3-resident: 25.6 MB)
__global__ void xconv_kernel(const float* __restrict__ x, ushort_t* __restrict__ xbf) {
  int i = blockIdx.x * blockDim.x + threadIdx.x;   // one float4 per thread
  floatx4 v = ldf4(x + (long)i * 4);
  ushort4v pk = {f2bf(v[0]), f2bf(v[1]), f2bf(v[2]), f2bf(v[3])};
  *(ushort4v*)(void*)(xbf + (long)i * 4) = pk;
}

// ---------------------------------------------------------------------------
// counting sort by dst: histogram -> 3-phase shfl scan -> scatter(perm)
// ---------------------------------------------------------------------------
__global__ void hist_kernel(const int* __restrict__ eidx, int* __restrict__ counts) {
  int e = blockIdx.x * blockDim.x + threadIdx.x;
  if (e < N_EDGES) atomicAdd(counts + eidx[N_EDGES + e], 1);
}

__global__ void scan_block_kernel(const int* __restrict__ counts,
                                  int* __restrict__ cur, int* __restrict__ bsum) {
  __shared__ int wsum[4];
  int i = blockIdx.x * 256 + threadIdx.x;
  int lane = threadIdx.x & 63, wave = threadIdx.x >> 6;
  int v = (i < N_NODES) ? counts[i] : 0;
  int s = v;
#pragma unroll
  for (int off = 1; off <= 32; off <<= 1) {
    int t = __shfl_up(s, off);
    if (lane >= off) s += t;
  }
  if (lane == 63) wsum[wave] = s;
  __syncthreads();
  int woff = 0;
  if (wave > 0) woff += wsum[0];
  if (wave > 1) woff += wsum[1];
  if (wave > 2) woff += wsum[2];
  if (i < N_NODES) cur[i] = s - v + woff;            // block-local exclusive
  if (threadIdx.x == 255) bsum[blockIdx.x] = s + woff;
}

__global__ void scan_total_kernel(const int* __restrict__ bsum, int* __restrict__ bofs) {
  __shared__ int wsum[4];
  int tid = threadIdx.x;
  int lane = tid & 63, wave = tid >> 6;
  int v = (tid < NB_SCAN) ? bsum[tid] : 0;
  int s = v;
#pragma unroll
  for (int off = 1; off <= 32; off <<= 1) {
    int t = __shfl_up(s, off);
    if (lane >= off) s += t;
  }
  if (lane == 63) wsum[wave] = s;
  __syncthreads();
  int woff = 0;
  if (wave > 0) woff += wsum[0];
  if (wave > 1) woff += wsum[1];
  if (wave > 2) woff += wsum[2];
  if (tid < NB_SCAN) bofs[tid] = s - v + woff;
}

__global__ void scan_add_kernel(int* __restrict__ cur, const int* __restrict__ bofs) {
  int i = blockIdx.x * 256 + threadIdx.x;
  if (i < N_NODES) cur[i] += bofs[i >> 8];
}

__global__ void scatter_kernel(const int* __restrict__ eidx, int* __restrict__ cur,
                               int* __restrict__ perm) {
  int e = blockIdx.x * blockDim.x + threadIdx.x;
  if (e < N_EDGES) {
    int d = eidx[N_EDGES + e];
    int pos = atomicAdd(cur + d, 1);
    perm[pos] = e;
  }
}

// ---------------------------------------------------------------------------
// staging helpers for the persistent edge kernel (registers only, no LDS)
// ---------------------------------------------------------------------------
__device__ __forceinline__ void load_tile_ptrs(long ebase, int tid,
                                               const int* __restrict__ perm,
                                               int (&pe4)[4], int& pe1) {
  int r0 = tid >> 4;
#pragma unroll
  for (int p = 0; p < 4; ++p) pe4[p] = perm[ebase + p * 16 + r0];
  if (tid < TILE_E) pe1 = perm[ebase + tid];
}

__device__ __forceinline__ void load_tile_data(int tid, const int (&pe4)[4], int pe1,
                                               const float* __restrict__ eattr,
                                               const int* __restrict__ eidx,
                                               ushort4v (&rawreg)[4], float& polreg,
                                               int& srcreg, int& dstreg) {
  int c = (tid & 15) * 4;
#pragma unroll
  for (int p = 0; p < 4; ++p) {
    const float* sp = eattr + (long)pe4[p] * 65 + 1 + c;
    rawreg[p] = (ushort4v){f2bf(sp[0]), f2bf(sp[1]), f2bf(sp[2]), f2bf(sp[3])};
  }
  if (tid < TILE_E) {
    polreg = eattr[(long)pe1 * 65];
    srcreg = eidx[pe1];
    dstreg = eidx[N_EDGES + pe1];
  }
}

// ---------------------------------------------------------------------------
// edge kernel: persistent blocks (3/CU), XCD-chunked contiguous tile ranges,
// carry-across-tiles one-shot aggr flush, JIT x-loads in the epilogue.
// amdgpu_waves_per_eu(3,3) pins the allocator to the occupancy LDS already
// caps us at (44 KB -> 3 blocks/CU = 3 waves/EU), granting the full
// ~168-VGPR budget. R7 evidence: allocator targeted the 6-wave tier
// (84 VGPR) while the cross-barrier live set (acc2 64 + pipeline regs ~16 +
// addressing) needs ~100 -> residual scratch spill traffic (~950 MB of the
// 1.61 GB FETCH was unexplained by intrinsic gather volume).
// ---------------------------------------------------------------------------
template <bool USEBF>
__global__ __launch_bounds__(256)
__attribute__((amdgpu_waves_per_eu(3, 3)))
void edge_kernel(const float* __restrict__ x,
                 const ushort_t* __restrict__ xbf,
                 const int* __restrict__ eidx,
                 const float* __restrict__ eattr,
                 const int* __restrict__ perm,
                 const ushort_t* __restrict__ We1bf,
                 const float* __restrict__ b_e1,
                 const float* __restrict__ b_le,
                 const ushort_t* __restrict__ Mw,
                 const float* __restrict__ cw,
                 float* __restrict__ aggr) {
  __shared__ __align__(16) ushort_t raw_lds[TILE_E * 72];
  __shared__ __align__(16) ushort_t t1_lds[TILE_E * 264];  // reused as msg f32
  __shared__ float pp_lds[TILE_E];
  __shared__ int src_lds[TILE_E];
  __shared__ int dst_lds[TILE_E + 1];

  const int tid  = threadIdx.x;
  const int lane = tid & 63;
  const int wave = tid >> 6;
  const int l16  = lane & 15;
  const int quad = lane >> 4;
  const int dbase = wave * 64;
  const int d_own = dbase + lane;

  // XCD-chunked, balanced tile range (bijective: 768 = 8 XCDs x 96)
  const int pb = blockIdx.x;
  const int lb = (pb & 7) * (NBLK_EDGE / 8) + (pb >> 3);
  const int q  = N_ETILES / NBLK_EDGE;                  // 16
  const int r  = N_ETILES % NBLK_EDGE;                  // 212
  const long tbeg = (long)lb * q + (lb < r ? lb : r);
  const long tend = tbeg + q + (lb < r ? 1 : 0);

  // prologue: stage first tile into registers
  int pe4[4], pe1 = 0;
  ushort4v rawreg[4];
  float polreg = 0.f;
  int srcreg = 0, dstreg = 0;
  load_tile_ptrs(tbeg * TILE_E, tid, perm, pe4, pe1);
  load_tile_data(tid, pe4, pe1, eattr, eidx, rawreg, polreg, srcreg, dstreg);

  float runsum = 0.f;        // carries across halves AND tiles
  bool first_flush = true;   // block's first flush -> atomic (shared boundary)

  for (long t = tbeg; t < tend; ++t) {
    const long tn = t + 1;
    const bool have_next = (tn < tend);

    // issue next tile's perm-pointer loads FIRST (covered by commit+A+GEMM1)
    if (have_next) load_tile_ptrs(tn * TILE_E, tid, perm, pe4, pe1);

    // ---- commit staged registers to LDS (current tile t)
    {
      int r0 = tid >> 4, c = (tid & 15) * 4;
#pragma unroll
      for (int p = 0; p < 4; ++p)
        *(ushort4v*)(void*)(raw_lds + (p * 16 + r0) * 72 + c) = rawreg[p];
      if (tid < TILE_E) {
        pp_lds[tid] = fminf(fmaxf(polreg, 0.f), 1.f) + 0.01f;
        src_lds[tid] = srcreg;
        dst_lds[tid] = dstreg;
      }
    }
    __syncthreads();   // A: staging visible

    // GEMM1 (transposed): t1^T[f][e]
    {
      floatx4 acc1[4][4];
#pragma unroll
      for (int m = 0; m < 4; ++m)
#pragma unroll
        for (int j = 0; j < 4; ++j) acc1[m][j] = (floatx4){0.f, 0.f, 0.f, 0.f};
#pragma unroll
      for (int kt = 0; kt < 2; ++kt) {
        short8 aW[4], bE[4];
#pragma unroll
        for (int m = 0; m < 4; ++m)
          aW[m] = ldg16(We1bf + (dbase + m * 16 + l16) * FEDGE + kt * 32 + quad * 8);
#pragma unroll
        for (int j = 0; j < 4; ++j)
          bE[j] = *(const short8*)(const void*)(raw_lds + (j * 16 + l16) * 72 + kt * 32 + quad * 8);
#pragma unroll
        for (int m = 0; m < 4; ++m)
#pragma unroll
          for (int j = 0; j < 4; ++j)
            acc1[m][j] = __builtin_amdgcn_mfma_f32_16x16x32_bf16(aW[m], bE[j], acc1[m][j], 0, 0, 0);
      }
#pragma unroll
      for (int m = 0; m < 4; ++m) {
        int f0 = dbase + m * 16 + quad * 4;
        floatx4 be1q = ldf4(b_e1 + f0);
#pragma unroll
        for (int j = 0; j < 4; ++j) {
          int e = j * 16 + l16;
          ushort4v pk = {f2bf(fmaxf(acc1[m][j][0] + be1q[0], 0.f)),
                         f2bf(fmaxf(acc1[m][j][1] + be1q[1], 0.f)),
                         f2bf(fmaxf(acc1[m][j][2] + be1q[2], 0.f)),
                         f2bf(fmaxf(acc1[m][j][3] + be1q[3], 0.f))};
          *(ushort4v*)(void*)(t1_lds + e * 264 + f0) = pk;
        }
      }
    }
    __syncthreads();   // B: t1 ready (acc1 dead here)

    // issue next tile's dependent gathers (covered by GEMM2)
    if (have_next)
      load_tile_data(tid, pe4, pe1, eattr, eidx, rawreg, polreg, srcreg, dstreg);

    // GEMM2 (transposed): pre^T[d][e]
    floatx4 acc2[4][4];
#pragma unroll
    for (int m = 0; m < 4; ++m)
#pragma unroll
      for (int j = 0; j < 4; ++j) acc2[m][j] = (floatx4){0.f, 0.f, 0.f, 0.f};
#pragma unroll
    for (int kt = 0; kt < 8; ++kt) {
      short8 aW[4], bE[4];
#pragma unroll
      for (int m = 0; m < 4; ++m)
        aW[m] = ldg16(Mw + (dbase + m * 16 + l16) * DMODEL + kt * 32 + quad * 8);
#pragma unroll
      for (int j = 0; j < 4; ++j)
        bE[j] = *(const short8*)(const void*)(t1_lds + (j * 16 + l16) * 264 + kt * 32 + quad * 8);
#pragma unroll
      for (int m = 0; m < 4; ++m)
#pragma unroll
        for (int j = 0; j < 4; ++j)
          acc2[m][j] = __builtin_amdgcn_mfma_f32_16x16x32_bf16(aW[m], bE[j], acc2[m][j], 0, 0, 0);
    }
    __syncthreads();   // C: t1 dead; LDS reused as per-wave msg buffer

    // publish next tile's first dst into the carry slot (read after barrier D/F)
    if (tid == 0) dst_lds[TILE_E] = have_next ? dstreg : -9;

    // JIT x[src] fragment loads: issued here (after C), consumed below.
    // Short live range -> sinkable by the scheduler -> no cross-barrier spill.
    ushort4v xq[4][4];
    floatx4  xqf[4][4];
#pragma unroll
    for (int j = 0; j < 4; ++j) {
      long srow = (long)src_lds[j * 16 + l16] * DMODEL;
#pragma unroll
      for (int m = 0; m < 4; ++m) {
        int d0 = dbase + m * 16 + quad * 4;
        if constexpr (USEBF)
          xq[j][m] = *(const ushort4v*)(const void*)(xbf + srow + d0);
        else
          xqf[j][m] = ldf4(x + srow + d0);
      }
    }

    floatx4 cv4[4], blv4[4];
#pragma unroll
    for (int m = 0; m < 4; ++m) {
      int d0 = dbase + m * 16 + quad * 4;
      cv4[m] = ldf4(cw + d0);
      blv4[m] = ldf4(b_le + d0);
    }
    float* msgw = ((float*)(void*)t1_lds) + wave * (64 * 33);

#pragma unroll
    for (int h = 0; h < 2; ++h) {
#pragma unroll
      for (int jj = 0; jj < 2; ++jj) {
        int j = h * 2 + jj;
        int e = j * 16 + l16;
        float pp = pp_lds[e];
#pragma unroll
        for (int m = 0; m < 4; ++m) {
          int d0 = m * 16 + quad * 4;
          float xr[4];
          if constexpr (USEBF) {
#pragma unroll
            for (int r2 = 0; r2 < 4; ++r2) xr[r2] = bf2f(xq[j][m][r2]);
          } else {
#pragma unroll
            for (int r2 = 0; r2 < 4; ++r2) xr[r2] = xqf[j][m][r2];
          }
#pragma unroll
          for (int r2 = 0; r2 < 4; ++r2)
            msgw[(d0 + r2) * 33 + jj * 16 + l16] =
                fmaxf(xr[r2] + pp * (acc2[m][j][r2] + cv4[m][r2]) + blv4[m][r2], 0.f);
        }
      }
      __syncthreads();   // D/F: msg ready
      for (int el = 0; el < 32; ++el) {
        int eg = h * 32 + el;
        runsum += msgw[lane * 33 + el];
        if (dst_lds[eg] != dst_lds[eg + 1]) {
          float* pdst = aggr + (long)dst_lds[eg] * DMODEL + d_own;
          const bool fin = (!have_next) && (eg == 63);  // block's final flush
          if (first_flush || fin) atomicAdd(pdst, runsum);
          else *pdst = runsum;   // interior dst: sole owner, complete sum
          first_flush = false;
          runsum = 0.f;
        }
      }
      __syncthreads();   // E/G: msg consumed (G also guards next-tile commit)
    }
  }
}

// ---------------------------------------------------------------------------
// node kernel, transposed; float4 I/O; in-register LN.
// ---------------------------------------------------------------------------
__global__ __launch_bounds__(256, 3)
void node_kernel(const float* __restrict__ x,
                 const float* __restrict__ aggr,
                 const ushort_t* __restrict__ Wg1bf,
                 const float* __restrict__ b_g1,
                 const float* __restrict__ ln_g,
                 const float* __restrict__ ln_b,
                 const ushort_t* __restrict__ Wg2bf,
                 const float* __restrict__ b_g2,
                 float* __restrict__ out) {
  __shared__ __align__(16) ushort_t a_lds[TILE_N * 264];
  __shared__ float ws_s[4][TILE_N];
  __shared__ float ws_ss[4][TILE_N];
  __shared__ float mu_lds[TILE_N], rs_lds[TILE_N];

  const int tid  = threadIdx.x;
  const int lane = tid & 63;
  const int wave = tid >> 6;
  const int l16  = lane & 15;
  const int quad = lane >> 4;
  const int dbase = wave * 64;
  const long nbase = (long)blockIdx.x * TILE_N;

#pragma unroll
  for (int i = 0; i < 16; ++i) {
    int id = tid + 256 * i;
    int r = id >> 6, c4 = (id & 63) * 4;
    long rr = nbase + r; if (rr >= N_NODES) rr = N_NODES - 1;
    floatx4 xv = ldf4(x + rr * DMODEL + c4);
    floatx4 av = ldf4(aggr + rr * DMODEL + c4);
    ushort4v pk = {f2bf(xv[0] + av[0]), f2bf(xv[1] + av[1]),
                   f2bf(xv[2] + av[2]), f2bf(xv[3] + av[3])};
    *(ushort4v*)(void*)(a_lds + r * 264 + c4) = pk;
  }
  __syncthreads();

  floatx4 acc[4][4];
#pragma unroll
  for (int m = 0; m < 4; ++m)
#pragma unroll
    for (int j = 0; j < 4; ++j) acc[m][j] = (floatx4){0.f, 0.f, 0.f, 0.f};
#pragma unroll
  for (int kt = 0; kt < 8; ++kt) {
    short8 aW[4], bN[4];
#pragma unroll
    for (int m = 0; m < 4; ++m)
      aW[m] = ldg16(Wg1bf + (dbase + m * 16 + l16) * DMODEL + kt * 32 + quad * 8);
#pragma unroll
    for (int j = 0; j < 4; ++j)
      bN[j] = *(const short8*)(const void*)(a_lds + (j * 16 + l16) * 264 + kt * 32 + quad * 8);
#pragma unroll
    for (int m = 0; m < 4; ++m)
#pragma unroll
      for (int j = 0; j < 4; ++j)
        acc[m][j] = __builtin_amdgcn_mfma_f32_16x16x32_bf16(aW[m], bN[j], acc[m][j], 0, 0, 0);
  }
#pragma unroll
  for (int m = 0; m < 4; ++m) {
    floatx4 bq = ldf4(b_g1 + dbase + m * 16 + quad * 4);
#pragma unroll
    for (int j = 0; j < 4; ++j)
#pragma unroll
      for (int r = 0; r < 4; ++r) acc[m][j][r] += bq[r];
  }

#pragma unroll
  for (int j = 0; j < 4; ++j) {
    float s = 0.f, ss = 0.f;
#pragma unroll
    for (int m = 0; m < 4; ++m)
#pragma unroll
      for (int r = 0; r < 4; ++r) { float v = acc[m][j][r]; s += v; ss += v * v; }
    s += __shfl_xor(s, 16); ss += __shfl_xor(ss, 16);
    s += __shfl_xor(s, 32); ss += __shfl_xor(ss, 32);
    if (quad == 0) { ws_s[wave][j * 16 + l16] = s; ws_ss[wave][j * 16 + l16] = ss; }
  }
  __syncthreads();
  if (tid < TILE_N) {
    float s = ws_s[0][tid] + ws_s[1][tid] + ws_s[2][tid] + ws_s[3][tid];
    float ss = ws_ss[0][tid] + ws_ss[1][tid] + ws_ss[2][tid] + ws_ss[3][tid];
    float mu = s * (1.f / 256.f);
    float var = ss * (1.f / 256.f) - mu * mu;
    mu_lds[tid] = mu;
    rs_lds[tid] = rsqrtf(var + 1e-5f);
  }
  __syncthreads();

#pragma unroll
  for (int m = 0; m < 4; ++m) {
    int d0 = dbase + m * 16 + quad * 4;
    floatx4 lg = ldf4(ln_g + d0), lb = ldf4(ln_b + d0);
#pragma unroll
    for (int j = 0; j < 4; ++j) {
      int e = j * 16 + l16;
      float mu = mu_lds[e], rs = rs_lds[e];
      ushort4v pk = {f2bf(fmaxf((acc[m][j][0] - mu) * rs * lg[0] + lb[0], 0.f)),
                     f2bf(fmaxf((acc[m][j][1] - mu) * rs * lg[1] + lb[1], 0.f)),
                     f2bf(fmaxf((acc[m][j][2] - mu) * rs * lg[2] + lb[2], 0.f)),
                     f2bf(fmaxf((acc[m][j][3] - mu) * rs * lg[3] + lb[3], 0.f))};
      *(ushort4v*)(void*)(a_lds + e * 264 + d0) = pk;
    }
  }
  __syncthreads();

#pragma unroll
  for (int m = 0; m < 4; ++m)
#pragma unroll
    for (int j = 0; j < 4; ++j) acc[m][j] = (floatx4){0.f, 0.f, 0.f, 0.f};
#pragma unroll
  for (int kt = 0; kt < 8; ++kt) {
    short8 aW[4], bN[4];
#pragma unroll
    for (int m = 0; m < 4; ++m)
      aW[m] = ldg16(Wg2bf + (dbase + m * 16 + l16) * DMODEL + kt * 32 + quad * 8);
#pragma unroll
    for (int j = 0; j < 4; ++j)
      bN[j] = *(const short8*)(const void*)(a_lds + (j * 16 + l16) * 264 + kt * 32 + quad * 8);
#pragma unroll
    for (int m = 0; m < 4; ++m)
#pragma unroll
      for (int j = 0; j < 4; ++j)
        acc[m][j] = __builtin_amdgcn_mfma_f32_16x16x32_bf16(aW[m], bN[j], acc[m][j], 0, 0, 0);
  }
#pragma unroll
  for (int m = 0; m < 4; ++m) {
    int d0 = dbase + m * 16 + quad * 4;
    floatx4 bq = ldf4(b_g2 + d0);
#pragma unroll
    for (int j = 0; j < 4; ++j) {
      long row = nbase + j * 16 + l16;
      if (row < N_NODES) {
        floatx4 o = {acc[m][j][0] + bq[0], acc[m][j][1] + bq[1],
                     acc[m][j][2] + bq[2], acc[m][j][3] + bq[3]};
        *(floatx4*)(void*)(out + row * DMODEL + d0) = o;
      }
    }
  }
}

// ---------------------------------------------------------------------------
extern "C" void kernel_launch(void* const* d_in, const int* in_sizes, int n_in,
                              void* d_out, int out_size, void* d_ws, size_t ws_size,
                              hipStream_t stream) {
  const float* x     = (const float*)d_in[0];
  const int*   eidx  = (const int*)d_in[1];
  const float* eattr = (const float*)d_in[2];
  const float* W_e1  = (const float*)d_in[3];
  const float* b_e1  = (const float*)d_in[4];
  const float* W_e2  = (const float*)d_in[5];
  const float* b_e2  = (const float*)d_in[6];
  const float* W_le  = (const float*)d_in[7];
  const float* b_le  = (const float*)d_in[8];
  const float* W_g1  = (const float*)d_in[9];
  const float* b_g1  = (const float*)d_in[10];
  const float* ln_g  = (const float*)d_in[11];
  const float* ln_b  = (const float*)d_in[12];
  const float* W_g2  = (const float*)d_in[13];
  const float* b_g2  = (const float*)d_in[14];
  float* out = (float*)d_out;

  char* ws = (char*)d_ws;
  ushort_t* Mw     = (ushort_t*)(ws);                 // 131072
  ushort_t* Wg1bf  = (ushort_t*)(ws + 131072);        // 131072
  ushort_t* Wg2bf  = (ushort_t*)(ws + 262144);        // 131072
  ushort_t* We1bf  = (ushort_t*)(ws + 393216);        // 32768
  float*    cw     = (float*)   (ws + 425984);        // 1024
  float*    aggr   = (float*)   (ws + 427008);        // 51,200,000
  int*      counts = (int*)     (ws + 51627008);      // 200,000
  int*      cur    = (int*)     (ws + 51827008);      // 200,000
  int*      perm   = (int*)     (ws + 52027008);      // 3,200,000
  int*      bsum   = (int*)     (ws + 55227008);      // 1,024
  int*      bofs   = (int*)     (ws + 55228032);      // 1,024
  ushort_t* xbf    = (ushort_t*)(ws + 55229056);      // 25,600,000 -> 80,829,056
  const size_t NEED_BF = 80829056;
  const bool use_bf = (ws_size >= NEED_BF);

  hipMemsetAsync(aggr, 0, (size_t)N_NODES * DMODEL * sizeof(float), stream);
  hipMemsetAsync(counts, 0, (size_t)N_NODES * sizeof(int), stream);
  prep_kernel<<<dim3(DMODEL), dim3(DMODEL), 0, stream>>>(
      W_le, W_e2, b_e2, W_e1, W_g1, W_g2, Mw, cw, We1bf, Wg1bf, Wg2bf);
  if (use_bf)
    xconv_kernel<<<dim3(N_NODES * DMODEL / 4 / 256), dim3(256), 0, stream>>>(x, xbf);
  hist_kernel<<<dim3((N_EDGES + 255) / 256), dim3(256), 0, stream>>>(eidx, counts);
  scan_block_kernel<<<dim3(NB_SCAN), dim3(256), 0, stream>>>(counts, cur, bsum);
  scan_total_kernel<<<dim3(1), dim3(256), 0, stream>>>(bsum, bofs);
  scan_add_kernel<<<dim3(NB_SCAN), dim3(256), 0, stream>>>(cur, bofs);
  scatter_kernel<<<dim3((N_EDGES + 255) / 256), dim3(256), 0, stream>>>(eidx, cur, perm);
  if (use_bf)
    edge_kernel<true><<<dim3(NBLK_EDGE), dim3(256), 0, stream>>>(
        x, xbf, eidx, eattr, perm, We1bf, b_e1, b_le, Mw, cw, aggr);
  else
    edge_kernel<false><<<dim3(NBLK_EDGE), dim3(256), 0, stream>>>(
        x, xbf, eidx, eattr, perm, We1bf, b_e1, b_le, Mw, cw, aggr);
  node_kernel<<<dim3(N_NTILES), dim3(256), 0, stream>>>(
      x, aggr, Wg1bf, b_g1, ln_g, ln_b, Wg2bf, b_g2, out);
}